// Round 2
// baseline (25372.717 us; speedup 1.0000x reference)
//
#include <hip/hip_runtime.h>
#include <stddef.h>

// LSTM encoder: B=64, T=512, H=512, L=4.
// R2: recurrent barrier rebuilt on relaxed agent-scope atomics (sc0/sc1 ->
// Infinity Cache coherence point) + explicit s_waitcnt vmcnt(0) ordering.
// No __threadfence (no buffer_wbl2/buffer_inv per step).
// Workspace layout (~209 MB):
//   INP fp32 [T,B,H]           64 MB
//   XW  fp16 [T*B,4H]         128 MB
//   WBF bf16 [L][4H][H] (B^T)   8 MB
//   UBF bf16 [L][4H][H] (B^T)   8 MB
//   HBF bf16 [2][B,H]         128 KB
//   cnt int  [L][T]             8 KB

typedef float          f32x4 __attribute__((ext_vector_type(4)));
typedef short          s16x8 __attribute__((ext_vector_type(8)));
typedef unsigned short u16;
typedef u16            u16x4 __attribute__((ext_vector_type(4)));
typedef _Float16       f16x4 __attribute__((ext_vector_type(4)));
typedef unsigned long long u64;

#define NWG 32

__device__ __forceinline__ u16 f2bf(float f) {
    unsigned int u = __builtin_bit_cast(unsigned int, f);
    u += 0x7FFFu + ((u >> 16) & 1u);   // round-to-nearest-even
    return (u16)(u >> 16);
}
__device__ __forceinline__ float sig(float x) { return 1.f / (1.f + __expf(-x)); }
__device__ __forceinline__ float th(float x)  { return 2.f / (1.f + __expf(-2.f * x)) - 1.f; }

__global__ void init_cnt(int* __restrict__ cnt) {
    for (int i = threadIdx.x; i < 4 * 512; i += 256) cnt[i] = 0;
}

// x[B,T,H] fp32 -> INP[T,B,H] fp32
__global__ void convert_x(const float* __restrict__ x, float* __restrict__ inp) {
#pragma unroll
    for (int i = 0; i < 8; ++i) {
        int f = blockIdx.x * 2048 + i * 256 + threadIdx.x;   // float4 index, 4.19M total
        int h4 = f & 127, b = (f >> 7) & 63, t = f >> 13;
        f32x4 v = *(const f32x4*)(x + ((size_t)b * 512 + t) * 512 + h4 * 4);
        *(f32x4*)(inp + ((size_t)t * 64 + b) * 512 + h4 * 4) = v;
    }
}

// W/U [l][k][n] fp32 -> [l][n][k] bf16 (transposed via LDS tile)
__global__ void convert_wu(const float* __restrict__ W, const float* __restrict__ U,
                           u16* __restrict__ WBF, u16* __restrict__ UBF) {
    __shared__ float tl[32][33];
    const int l = blockIdx.z & 3, which = blockIdx.z >> 2;
    const float* src = (which ? U : W) + (size_t)l * 512 * 2048;
    u16* dst = (which ? UBF : WBF) + (size_t)l * 2048 * 512;
    const int n0 = blockIdx.x * 32, k0 = blockIdx.y * 32;
    const int tid = threadIdx.x;
    const int r = tid >> 3, c4 = (tid & 7) * 4;
    f32x4 v = *(const f32x4*)(src + (size_t)(k0 + r) * 2048 + n0 + c4);
    tl[r][c4 + 0] = v[0]; tl[r][c4 + 1] = v[1]; tl[r][c4 + 2] = v[2]; tl[r][c4 + 3] = v[3];
    __syncthreads();
    u16x4 o = { f2bf(tl[c4 + 0][r]), f2bf(tl[c4 + 1][r]), f2bf(tl[c4 + 2][r]), f2bf(tl[c4 + 3][r]) };
    *(u16x4*)(dst + (size_t)(n0 + r) * 512 + k0 + c4) = o;
}

// C[M=32768,N=2048] fp16 = A[M,512] fp32 (convert) @ Bt^T (Bt = [N][K] bf16) + bias
__global__ __launch_bounds__(256) void gemm_xw(const float* __restrict__ A,
                                               const u16* __restrict__ Bt,
                                               const float* __restrict__ bias,
                                               _Float16* __restrict__ C) {
    __shared__ u16 Alds[128][72];
    __shared__ u16 Blds[128][72];
    const int tid = threadIdx.x, lane = tid & 63, wave = tid >> 6;
    const int m0 = blockIdx.y * 128, n0 = blockIdx.x * 128;
    const int wm = (wave & 1) * 64, wn = (wave >> 1) * 64;
    const int m_l = lane & 15, k_l = (lane >> 4) * 8, r0 = (lane >> 4) * 4;
    f32x4 acc[4][4] = {};
    for (int k0 = 0; k0 < 512; k0 += 64) {
        __syncthreads();
#pragma unroll
        for (int i = 0; i < 8; ++i) {                       // stage A (fp32 -> bf16)
            int f = tid + i * 256;
            int row = f >> 4, c4 = (f & 15) * 4;
            f32x4 v = *(const f32x4*)(A + (size_t)(m0 + row) * 512 + k0 + c4);
            u16x4 bv = { f2bf(v[0]), f2bf(v[1]), f2bf(v[2]), f2bf(v[3]) };
            *(u16x4*)&Alds[row][c4] = bv;
        }
#pragma unroll
        for (int i = 0; i < 4; ++i) {                       // stage B (bf16, B^T rows)
            int f = tid + i * 256;
            int row = f >> 3, c8 = (f & 7) * 8;
            *(s16x8*)&Blds[row][c8] = *(const s16x8*)(Bt + (size_t)(n0 + row) * 512 + k0 + c8);
        }
        __syncthreads();
#pragma unroll
        for (int kk = 0; kk < 2; ++kk) {
            s16x8 af[4], bfr[4];
            const int kb = kk * 32 + k_l;
#pragma unroll
            for (int mi = 0; mi < 4; ++mi) af[mi]  = *(const s16x8*)&Alds[wm + mi * 16 + m_l][kb];
#pragma unroll
            for (int ni = 0; ni < 4; ++ni) bfr[ni] = *(const s16x8*)&Blds[wn + ni * 16 + m_l][kb];
#pragma unroll
            for (int mi = 0; mi < 4; ++mi)
#pragma unroll
                for (int ni = 0; ni < 4; ++ni)
                    acc[mi][ni] = __builtin_amdgcn_mfma_f32_16x16x32_bf16(af[mi], bfr[ni], acc[mi][ni], 0, 0, 0);
        }
    }
#pragma unroll
    for (int ni = 0; ni < 4; ++ni) {
        const int col = n0 + wn + ni * 16 + m_l;
        const float bb = bias[col];
#pragma unroll
        for (int mi = 0; mi < 4; ++mi)
#pragma unroll
            for (int r = 0; r < 4; ++r) {
                const int m = m0 + wm + mi * 16 + r0 + r;
                C[(size_t)m * 2048 + col] = (_Float16)(acc[mi][ni][r] + bb);
            }
    }
}

// Persistent recurrent kernel: 32 WGs x 256 thr. WG wg owns hidden units
// [16*wg, 16*wg+16); wave w computes gate w. U B-frags in VGPRs for all 512 steps.
// Cross-WG h exchange: relaxed agent-scope atomics (coherence-point accesses),
// ordering via explicit s_waitcnt vmcnt(0). No cache-flushing fences.
__global__ __launch_bounds__(256) void recur(const _Float16* __restrict__ XW,
                                             const u16* __restrict__ UBF_l,
                                             float* __restrict__ INP,
                                             u64* __restrict__ HBF,   // [2][64][128] u64
                                             int* __restrict__ cnt,
                                             float* __restrict__ states,
                                             const int layer) {
    __shared__ u16  h_lds[64][264];        // K=256 chunk of h, +8 pad (row = 66 u64)
    __shared__ float z_lds[4][64][17];     // [gate][batch][unit_local], +1 pad
    const int tid = threadIdx.x, lane = tid & 63, wave = tid >> 6;
    const int wg = blockIdx.x;
    const int m_l = lane & 15, k_l = (lane >> 4) * 8, r0 = (lane >> 4) * 4;

    // preload U fragments: col = wave*512 + wg*16 + (lane&15), MFMA B-frag layout
    s16x8 ufrag[16];
    {
        const u16* ub = UBF_l + ((size_t)(wave * 512 + wg * 16 + m_l)) * 512 + k_l;
#pragma unroll
        for (int kf = 0; kf < 16; ++kf) ufrag[kf] = *(const s16x8*)(ub + kf * 32);
    }
    for (int i = tid; i < 64 * 264; i += 256) ((u16*)h_lds)[i] = 0;   // h0 = 0

    const int gb = tid >> 2;           // batch row in gate phase
    const int ug = (tid & 3) * 4;      // unit-local base (4 units per thread)
    const int u  = wg * 16 + ug;       // global unit base
    float cr[4] = {0.f, 0.f, 0.f, 0.f};

    for (int t = 0; t < 512; ++t) {
        // prefetch this step's XW slice before waiting on the flag
        const _Float16* xwp = XW + ((size_t)t * 64 + gb) * 2048 + u;
        f16x4 xi = *(const f16x4*)(xwp);
        f16x4 xf = *(const f16x4*)(xwp + 512);
        f16x4 xg = *(const f16x4*)(xwp + 1024);
        f16x4 xo = *(const f16x4*)(xwp + 1536);

        f32x4 acc[4] = {};
        if (t > 0) {
            if (tid == 0) {
                while (__hip_atomic_load(&cnt[t - 1], __ATOMIC_RELAXED, __HIP_MEMORY_SCOPE_AGENT) < NWG) { }
            }
            __syncthreads();           // all threads gated on the flag
        }
        const u64* src = HBF + ((t - 1) & 1) * (64 * 128);   // [64][128] u64
#pragma unroll
        for (int half = 0; half < 2; ++half) {
            if (t > 0) {
                __syncthreads();   // previous chunk's MFMA reads done
#pragma unroll
                for (int i = 0; i < 16; ++i) {
                    int j = tid + i * 256;           // u64 index in [64][64] chunk
                    int b = j >> 6, kq = j & 63;
                    u64 v = __hip_atomic_load(src + b * 128 + half * 64 + kq,
                                              __ATOMIC_RELAXED, __HIP_MEMORY_SCOPE_AGENT);
                    *(u64*)&h_lds[b][kq * 4] = v;
                }
            }
            __syncthreads();
#pragma unroll
            for (int kf = 0; kf < 8; ++kf) {
#pragma unroll
                for (int mt = 0; mt < 4; ++mt) {
                    s16x8 af = *(const s16x8*)&h_lds[mt * 16 + m_l][kf * 32 + k_l];
                    acc[mt] = __builtin_amdgcn_mfma_f32_16x16x32_bf16(af, ufrag[half * 8 + kf], acc[mt], 0, 0, 0);
                }
            }
        }
        // z -> LDS (C-layout: col=lane&15 -> unit_local, row -> batch)
#pragma unroll
        for (int mt = 0; mt < 4; ++mt)
#pragma unroll
            for (int r = 0; r < 4; ++r)
                z_lds[wave][mt * 16 + r0 + r][m_l] = acc[mt][r];
        __syncthreads();

        // gate phase: thread handles 4 units of batch row gb
        float h[4];
#pragma unroll
        for (int j = 0; j < 4; ++j) {
            float zi = (float)xi[j] + z_lds[0][gb][ug + j];
            float zf = (float)xf[j] + z_lds[1][gb][ug + j];
            float zg = (float)xg[j] + z_lds[2][gb][ug + j];
            float zo = (float)xo[j] + z_lds[3][gb][ug + j];
            float cc = sig(zf) * cr[j] + sig(zi) * th(zg);
            cr[j] = cc;
            h[j] = sig(zo) * th(cc);
        }
        // publish h (coherence-point store, 4 bf16 packed in one u64)
        u16x4 hb = { f2bf(h[0]), f2bf(h[1]), f2bf(h[2]), f2bf(h[3]) };
        u64 hv64 = __builtin_bit_cast(u64, hb);
        __hip_atomic_store(HBF + (t & 1) * (64 * 128) + gb * 128 + (u >> 2), hv64,
                           __ATOMIC_RELAXED, __HIP_MEMORY_SCOPE_AGENT);
        const size_t oidx = ((size_t)t * 64 + gb) * 512 + u;
        f32x4 hv = { h[0], h[1], h[2], h[3] };
        if (layer) hv += *(const f32x4*)&INP[oidx];
        *(f32x4*)&INP[oidx] = hv;
        if (layer == 0 && t == 511) {
#pragma unroll
            for (int rep = 0; rep < 4; ++rep)
                *(f32x4*)&states[rep * (64 * 512) + gb * 512 + u] = hv;
        }
        // order: h stores must reach the coherence point before the flag bump
        asm volatile("s_waitcnt vmcnt(0)" ::: "memory");
        __syncthreads();
        if (tid == 0)
            __hip_atomic_fetch_add(&cnt[t], 1, __ATOMIC_RELAXED, __HIP_MEMORY_SCOPE_AGENT);
    }
}

// INP[T,B,H] -> out[B,T,H]
__global__ void transpose_out(const float* __restrict__ inp, float* __restrict__ out) {
#pragma unroll
    for (int i = 0; i < 8; ++i) {
        int f = blockIdx.x * 2048 + i * 256 + threadIdx.x;
        int h4 = f & 127, t = (f >> 7) & 511, b = f >> 16;
        f32x4 v = *(const f32x4*)(inp + ((size_t)t * 64 + b) * 512 + h4 * 4);
        *(f32x4*)(out + ((size_t)b * 512 + t) * 512 + h4 * 4) = v;
    }
}

extern "C" void kernel_launch(void* const* d_in, const int* in_sizes, int n_in,
                              void* d_out, int out_size, void* d_ws, size_t ws_size,
                              hipStream_t stream) {
    const float* x = (const float*)d_in[0];
    const float* W = (const float*)d_in[1];
    const float* U = (const float*)d_in[2];
    const float* b = (const float*)d_in[3];
    float* out = (float*)d_out;
    char* ws = (char*)d_ws;

    constexpr size_t INP_OFF = 0;
    constexpr size_t XW_OFF  = 67108864;       // 64 MB
    constexpr size_t WBF_OFF = XW_OFF + 134217728;
    constexpr size_t UBF_OFF = WBF_OFF + 8388608;
    constexpr size_t HBF_OFF = UBF_OFF + 8388608;
    constexpr size_t CNT_OFF = HBF_OFF + 131072;

    float*     INP = (float*)(ws + INP_OFF);
    _Float16*  XW  = (_Float16*)(ws + XW_OFF);
    u16*       WBF = (u16*)(ws + WBF_OFF);
    u16*       UBF = (u16*)(ws + UBF_OFF);
    u64*       HBF = (u64*)(ws + HBF_OFF);
    int*       cnt = (int*)(ws + CNT_OFF);

    init_cnt<<<1, 256, 0, stream>>>(cnt);
    convert_x<<<2048, 256, 0, stream>>>(x, INP);
    convert_wu<<<dim3(64, 16, 8), 256, 0, stream>>>(W, U, WBF, UBF);

    for (int l = 0; l < 4; ++l) {
        gemm_xw<<<dim3(16, 256), 256, 0, stream>>>(INP, WBF + (size_t)l * 1048576,
                                                   b + (size_t)l * 2048, XW);
        recur<<<NWG, 256, 0, stream>>>(XW, UBF + (size_t)l * 1048576, INP, HBF,
                                       cnt + l * 512, out + 16777216, l);
    }
    transpose_out<<<2048, 256, 0, stream>>>(INP, out);
}

// Round 5
// 15476.918 us; speedup vs baseline: 1.6394x; 1.6394x over previous
//
#include <hip/hip_runtime.h>
#include <stddef.h>

// LSTM encoder: B=64, T=512, H=512, L=4.
// R5 = R4 with the hring slot-stride bug fixed: a slot is [64][128] u64
// (64 KB = 8192 u64), so slot offset is ((buf*4+l) << 13) u64, not << 12.
// R4's << 12 made slots overlap pairwise -> cross-layer h corruption
// (deterministic absmax 0.47). Everything else identical to R4.
//
// Structure: 128 WGs = 4 layer-groups x 32. Group l, WG wg owns hidden
// units [16wg,16wg+16); wave = gate. U (and W for l>0) live in VGPRs as
// MFMA B-frags. Layer 0's x-projection precomputed by GEMM (per-(t,wg)
// contiguous slices); layers>=1 compute x@W on the fly from the fp32
// residual chain INP (in-place overwrite). Cross-WG: relaxed agent-scope
// atomics + s_waitcnt vmcnt(0) before per-WG flags; one-vmem ballot polls.
// Workspace (~208.8 MB):
//   XW    fp16 [T][32][4][64][16]  128 MB  (read-only in fused)
//   INP   fp32 [T,B,H]              64 MB  (x -> out_0 -> ... -> out_3)
//   WBF   bf16 [L][4H][H] (B^T)      8 MB
//   UBF   bf16 [L][4H][H] (B^T)      8 MB
//   FLG   int  [L][513][32]        257 KB
//   HRING bf16 [2][L][64][512]     512 KB  (depth-2 per layer)

typedef float          f32x4 __attribute__((ext_vector_type(4)));
typedef short          s16x8 __attribute__((ext_vector_type(8)));
typedef unsigned short u16;
typedef u16            u16x4 __attribute__((ext_vector_type(4)));
typedef _Float16       f16x4 __attribute__((ext_vector_type(4)));
typedef unsigned long long u64;

__device__ __forceinline__ u16 f2bf(float f) {
    unsigned int u = __builtin_bit_cast(unsigned int, f);
    u += 0x7FFFu + ((u >> 16) & 1u);   // round-to-nearest-even
    return (u16)(u >> 16);
}
__device__ __forceinline__ float sig(float x) { return 1.f / (1.f + __expf(-x)); }
__device__ __forceinline__ float th(float x)  { return 2.f / (1.f + __expf(-2.f * x)) - 1.f; }
__device__ __forceinline__ u64 pk2(float a, float b) {
    return (u64)__builtin_bit_cast(unsigned, a) | ((u64)__builtin_bit_cast(unsigned, b) << 32);
}
__device__ __forceinline__ float lo32(u64 v) { return __builtin_bit_cast(float, (unsigned)v); }
__device__ __forceinline__ float hi32(u64 v) { return __builtin_bit_cast(float, (unsigned)(v >> 32)); }

// all-lane flag poll: lanes with active==false auto-pass
__device__ __forceinline__ void pollflags(const int* p, bool active) {
    while (1) {
        int v = 1;
        if (active) v = __hip_atomic_load(p, __ATOMIC_RELAXED, __HIP_MEMORY_SCOPE_AGENT);
        if (__ballot(v != 0) == ~0ull) break;
    }
}

__global__ void init_flags(int* __restrict__ flg) {
    int i = blockIdx.x * 256 + threadIdx.x;
    if (i < 4 * 513 * 32) flg[i] = 0;
}

// x[B,T,H] fp32 -> INP[T,B,H] fp32
__global__ void convert_x(const float* __restrict__ x, float* __restrict__ inp) {
#pragma unroll
    for (int i = 0; i < 8; ++i) {
        int f = blockIdx.x * 2048 + i * 256 + threadIdx.x;
        int h4 = f & 127, b = (f >> 7) & 63, t = f >> 13;
        f32x4 v = *(const f32x4*)(x + ((size_t)b * 512 + t) * 512 + h4 * 4);
        *(f32x4*)(inp + ((size_t)t * 64 + b) * 512 + h4 * 4) = v;
    }
}

// W/U [l][k][n] fp32 -> [l][n][k] bf16 (transposed via LDS tile)
__global__ void convert_wu(const float* __restrict__ W, const float* __restrict__ U,
                           u16* __restrict__ WBF, u16* __restrict__ UBF) {
    __shared__ float tl[32][33];
    const int l = blockIdx.z & 3, which = blockIdx.z >> 2;
    const float* src = (which ? U : W) + (size_t)l * 512 * 2048;
    u16* dst = (which ? UBF : WBF) + (size_t)l * 2048 * 512;
    const int n0 = blockIdx.x * 32, k0 = blockIdx.y * 32;
    const int tid = threadIdx.x;
    const int r = tid >> 3, c4 = (tid & 7) * 4;
    f32x4 v = *(const f32x4*)(src + (size_t)(k0 + r) * 2048 + n0 + c4);
    tl[r][c4 + 0] = v[0]; tl[r][c4 + 1] = v[1]; tl[r][c4 + 2] = v[2]; tl[r][c4 + 3] = v[3];
    __syncthreads();
    u16x4 o = { f2bf(tl[c4 + 0][r]), f2bf(tl[c4 + 1][r]), f2bf(tl[c4 + 2][r]), f2bf(tl[c4 + 3][r]) };
    *(u16x4*)(dst + (size_t)(n0 + r) * 512 + k0 + c4) = o;
}

// layer-0 xW: C fp16 = A[32768,512] fp32 @ Bt^T + bias, output in
// [t][wg][gate][b][ul] layout (per-(t,wg) contiguous 8KB slices)
__global__ __launch_bounds__(256) void gemm_xw(const float* __restrict__ A,
                                               const u16* __restrict__ Bt,
                                               const float* __restrict__ bias,
                                               _Float16* __restrict__ C) {
    __shared__ u16 Alds[128][72];
    __shared__ u16 Blds[128][72];
    const int tid = threadIdx.x, lane = tid & 63, wave = tid >> 6;
    const int m0 = blockIdx.y * 128, n0 = blockIdx.x * 128;
    const int wm = (wave & 1) * 64, wn = (wave >> 1) * 64;
    const int m_l = lane & 15, k_l = (lane >> 4) * 8, r0 = (lane >> 4) * 4;
    f32x4 acc[4][4] = {};
    for (int k0 = 0; k0 < 512; k0 += 64) {
        __syncthreads();
#pragma unroll
        for (int i = 0; i < 8; ++i) {
            int f = tid + i * 256;
            int row = f >> 4, c4 = (f & 15) * 4;
            f32x4 v = *(const f32x4*)(A + (size_t)(m0 + row) * 512 + k0 + c4);
            u16x4 bv = { f2bf(v[0]), f2bf(v[1]), f2bf(v[2]), f2bf(v[3]) };
            *(u16x4*)&Alds[row][c4] = bv;
        }
#pragma unroll
        for (int i = 0; i < 4; ++i) {
            int f = tid + i * 256;
            int row = f >> 3, c8 = (f & 7) * 8;
            *(s16x8*)&Blds[row][c8] = *(const s16x8*)(Bt + (size_t)(n0 + row) * 512 + k0 + c8);
        }
        __syncthreads();
#pragma unroll
        for (int kk = 0; kk < 2; ++kk) {
            s16x8 af[4], bfr[4];
            const int kb = kk * 32 + k_l;
#pragma unroll
            for (int mi = 0; mi < 4; ++mi) af[mi]  = *(const s16x8*)&Alds[wm + mi * 16 + m_l][kb];
#pragma unroll
            for (int ni = 0; ni < 4; ++ni) bfr[ni] = *(const s16x8*)&Blds[wn + ni * 16 + m_l][kb];
#pragma unroll
            for (int mi = 0; mi < 4; ++mi)
#pragma unroll
                for (int ni = 0; ni < 4; ++ni)
                    acc[mi][ni] = __builtin_amdgcn_mfma_f32_16x16x32_bf16(af[mi], bfr[ni], acc[mi][ni], 0, 0, 0);
        }
    }
#pragma unroll
    for (int ni = 0; ni < 4; ++ni) {
        const int col = n0 + wn + ni * 16 + m_l;
        const float bb = bias[col];
        const int gate = col >> 9, uu = col & 511, wgi = uu >> 4, ul = uu & 15;
#pragma unroll
        for (int mi = 0; mi < 4; ++mi)
#pragma unroll
            for (int r = 0; r < 4; ++r) {
                const int m = m0 + wm + mi * 16 + r0 + r;
                const int t = m >> 6, brow = m & 63;
                C[(((size_t)t * 32 + wgi) * 4 + gate) * 1024 + brow * 16 + ul] =
                    (_Float16)(acc[mi][ni][r] + bb);
            }
    }
}

// Fused persistent kernel: 128 WGs = 4 layer-groups x 32.
__global__ __launch_bounds__(256) void fused(const _Float16* __restrict__ XW,
                                             const u16* __restrict__ WBF,
                                             const u16* __restrict__ UBF,
                                             const float* __restrict__ bias,
                                             float* __restrict__ INP,
                                             int* __restrict__ flg,
                                             u64* __restrict__ hring,   // [2][4][64][128] u64
                                             float* __restrict__ states) {
    __shared__ char uni[33792];            // h_lds [64][264] u16  UNION  z_lds [4][64][16] f32
    __shared__ u16 xw_lds[4096];           // layer-0 xW slice [gate][b][ul]
    u16 (*h_lds)[264] = (u16(*)[264])uni;
    float* z_lds = (float*)uni;

    const int tid = threadIdx.x, lane = tid & 63, wave = tid >> 6;
    const int l = blockIdx.x & 3, wg = blockIdx.x >> 2;
    const int m_l = lane & 15, k_l = (lane >> 4) * 8, r0 = (lane >> 4) * 4;
    const int gb = tid >> 2, ug = (tid & 3) * 4, u = wg * 16 + ug;

    // weight fragments in VGPRs (MFMA B-frag layout)
    s16x8 ufrag[16], wfrag[16];
    {
        const u16* ub = UBF + (size_t)l * 1048576 + ((size_t)(wave * 512 + wg * 16 + m_l)) * 512 + k_l;
#pragma unroll
        for (int kf = 0; kf < 16; ++kf) ufrag[kf] = *(const s16x8*)(ub + kf * 32);
    }
    if (l > 0) {
        const u16* wb = WBF + (size_t)l * 1048576 + ((size_t)(wave * 512 + wg * 16 + m_l)) * 512 + k_l;
#pragma unroll
        for (int kf = 0; kf < 16; ++kf) wfrag[kf] = *(const s16x8*)(wb + kf * 32);
    }
    float bj[4][4];
#pragma unroll
    for (int g = 0; g < 4; ++g)
#pragma unroll
        for (int j = 0; j < 4; ++j)
            bj[g][j] = (l > 0) ? bias[(size_t)l * 2048 + g * 512 + u + j] : 0.f;

    s16x8 xr0 = {}, xr1 = {};              // one-step-ahead XW stage regs (l==0)
    if (l == 0) {
        const s16x8* p = (const s16x8*)(XW + (size_t)wg * 4096 + tid * 16);
        xr0 = p[0]; xr1 = p[1];
    }

    float cr[4] = {0.f, 0.f, 0.f, 0.f};
    float hprev[4] = {0.f, 0.f, 0.f, 0.f};

    for (int t = 0; t <= 512; ++t) {
        // stage this step's XW into LDS; issue next step's loads (l==0)
        if (l == 0 && t < 512) {
            *(s16x8*)&xw_lds[tid * 16] = xr0;
            *(s16x8*)&xw_lds[tid * 16 + 8] = xr1;
            if (t < 511) {
                const s16x8* p = (const s16x8*)(XW + ((size_t)(t + 1) * 32 + wg) * 4096 + tid * 16);
                xr0 = p[0]; xr1 = p[1];
            }
        }
        // poll A: x availability (producer's step t+1 flag certifies out_{l-1}[t])
        const int th_ = (t < 512) ? t + 1 : 512;
        pollflags(flg + (((l - 1) * 513 + th_) * 32 + (lane & 31)), (lane >= 32) && (l > 0));

        f32x4 acc[4] = {};
        if (t < 512 && l > 0) {            // x phases: z += x@W, x = out_{l-1}[t] fp32
            const u64* xsrc = (const u64*)(INP + (size_t)t * 32768);
#pragma unroll
            for (int half = 0; half < 2; ++half) {
                __syncthreads();
#pragma unroll
                for (int i = 0; i < 32; ++i) {
                    int j = tid + i * 256;             // [0,8192)
                    int bb = j >> 7, kq = j & 127;
                    u64 v = __hip_atomic_load(xsrc + bb * 256 + half * 128 + kq,
                                              __ATOMIC_RELAXED, __HIP_MEMORY_SCOPE_AGENT);
                    unsigned pkv = (unsigned)f2bf(lo32(v)) | ((unsigned)f2bf(hi32(v)) << 16);
                    *(unsigned*)&h_lds[bb][kq * 2] = pkv;
                }
                __syncthreads();
#pragma unroll
                for (int kf = 0; kf < 8; ++kf)
#pragma unroll
                    for (int mt = 0; mt < 4; ++mt) {
                        s16x8 af = *(const s16x8*)&h_lds[mt * 16 + m_l][kf * 32 + k_l];
                        acc[mt] = __builtin_amdgcn_mfma_f32_16x16x32_bf16(af, wfrag[half * 8 + kf], acc[mt], 0, 0, 0);
                    }
            }
        }
        // poll B: own recurrence (all 32 WGs of this group finished step t-1)
        pollflags(flg + ((l * 513 + (t - 1)) * 32 + (lane & 31)), (lane < 32) && (t > 0));

        // publish out_l[t-1] = hprev (+ residual) into INP (safe after poll B)
        if (t > 0) {
            u64* op = (u64*)(INP + (size_t)(t - 1) * 32768 + gb * 512 + u);
            float o0 = hprev[0], o1 = hprev[1], o2 = hprev[2], o3 = hprev[3];
            if (l > 0) {
                u64 a = __hip_atomic_load(op,     __ATOMIC_RELAXED, __HIP_MEMORY_SCOPE_AGENT);
                u64 b2 = __hip_atomic_load(op + 1, __ATOMIC_RELAXED, __HIP_MEMORY_SCOPE_AGENT);
                o0 += lo32(a); o1 += hi32(a); o2 += lo32(b2); o3 += hi32(b2);
            }
            __hip_atomic_store(op,     pk2(o0, o1), __ATOMIC_RELAXED, __HIP_MEMORY_SCOPE_AGENT);
            __hip_atomic_store(op + 1, pk2(o2, o3), __ATOMIC_RELAXED, __HIP_MEMORY_SCOPE_AGENT);
            if (l == 0 && t == 512) {
                f32x4 sv = { o0, o1, o2, o3 };
#pragma unroll
                for (int rep = 0; rep < 4; ++rep)
                    *(f32x4*)&states[(size_t)rep * 32768 + gb * 512 + u] = sv;
            }
        }

        if (t < 512) {
            if (t > 0) {                   // h phases: z += h_{t-1}@U  (ring slot ((t-1)&1, l))
                const u64* hsrc = hring + (((size_t)((t - 1) & 1) * 4 + l) << 13);
#pragma unroll
                for (int half = 0; half < 2; ++half) {
                    __syncthreads();
#pragma unroll
                    for (int i = 0; i < 16; ++i) {
                        int j = tid + i * 256;         // [0,4096)
                        int bb = j >> 6, kq = j & 63;
                        u64 v = __hip_atomic_load(hsrc + bb * 128 + half * 64 + kq,
                                                  __ATOMIC_RELAXED, __HIP_MEMORY_SCOPE_AGENT);
                        *(u64*)&h_lds[bb][kq * 4] = v;
                    }
                    __syncthreads();
#pragma unroll
                    for (int kf = 0; kf < 8; ++kf)
#pragma unroll
                        for (int mt = 0; mt < 4; ++mt) {
                            s16x8 af = *(const s16x8*)&h_lds[mt * 16 + m_l][kf * 32 + k_l];
                            acc[mt] = __builtin_amdgcn_mfma_f32_16x16x32_bf16(af, ufrag[half * 8 + kf], acc[mt], 0, 0, 0);
                        }
                }
            }
            __syncthreads();               // h_lds reads done; safe to overwrite union with z
#pragma unroll
            for (int mt = 0; mt < 4; ++mt)
#pragma unroll
                for (int r = 0; r < 4; ++r)
                    z_lds[wave * 1024 + (mt * 16 + r0 + r) * 16 + m_l] = acc[mt][r];
            __syncthreads();

            // gate phase: thread handles 4 units of batch row gb
            float h[4];
#pragma unroll
            for (int j = 0; j < 4; ++j) {
                float zi = z_lds[0 * 1024 + gb * 16 + ug + j];
                float zf = z_lds[1 * 1024 + gb * 16 + ug + j];
                float zg = z_lds[2 * 1024 + gb * 16 + ug + j];
                float zo = z_lds[3 * 1024 + gb * 16 + ug + j];
                if (l == 0) {
                    zi += (float)*(const _Float16*)&xw_lds[0 * 1024 + gb * 16 + ug + j];
                    zf += (float)*(const _Float16*)&xw_lds[1 * 1024 + gb * 16 + ug + j];
                    zg += (float)*(const _Float16*)&xw_lds[2 * 1024 + gb * 16 + ug + j];
                    zo += (float)*(const _Float16*)&xw_lds[3 * 1024 + gb * 16 + ug + j];
                } else {
                    zi += bj[0][j]; zf += bj[1][j]; zg += bj[2][j]; zo += bj[3][j];
                }
                float cc = sig(zf) * cr[j] + sig(zi) * th(zg);
                cr[j] = cc;
                h[j] = sig(zo) * th(cc);
            }
            // publish h -> ring slot (t&1, l)
            u16x4 hb = { f2bf(h[0]), f2bf(h[1]), f2bf(h[2]), f2bf(h[3]) };
            u64 hv64 = __builtin_bit_cast(u64, hb);
            __hip_atomic_store(hring + (((size_t)(t & 1) * 4 + l) << 13) + gb * 128 + (u >> 2),
                               hv64, __ATOMIC_RELAXED, __HIP_MEMORY_SCOPE_AGENT);
#pragma unroll
            for (int j = 0; j < 4; ++j) hprev[j] = h[j];
        }

        // drain all stores/stage-loads, then raise this WG's flag for step t
        asm volatile("s_waitcnt vmcnt(0)" ::: "memory");
        __syncthreads();
        if (tid == 0)
            __hip_atomic_store(flg + (l * 513 + t) * 32 + wg, 1,
                               __ATOMIC_RELAXED, __HIP_MEMORY_SCOPE_AGENT);
    }
}

// INP[T,B,H] -> out[B,T,H]
__global__ void transpose_out(const float* __restrict__ inp, float* __restrict__ out) {
#pragma unroll
    for (int i = 0; i < 8; ++i) {
        int f = blockIdx.x * 2048 + i * 256 + threadIdx.x;
        int h4 = f & 127, t = (f >> 7) & 511, b = f >> 16;
        f32x4 v = *(const f32x4*)(inp + ((size_t)t * 64 + b) * 512 + h4 * 4);
        *(f32x4*)(out + ((size_t)b * 512 + t) * 512 + h4 * 4) = v;
    }
}

extern "C" void kernel_launch(void* const* d_in, const int* in_sizes, int n_in,
                              void* d_out, int out_size, void* d_ws, size_t ws_size,
                              hipStream_t stream) {
    const float* x = (const float*)d_in[0];
    const float* W = (const float*)d_in[1];
    const float* U = (const float*)d_in[2];
    const float* b = (const float*)d_in[3];
    float* out = (float*)d_out;
    char* ws = (char*)d_ws;

    constexpr size_t XW_OFF  = 0;                          // 134,217,728
    constexpr size_t INP_OFF = 134217728;                  //  67,108,864
    constexpr size_t WBF_OFF = INP_OFF + 67108864;         //   8,388,608
    constexpr size_t UBF_OFF = WBF_OFF + 8388608;          //   8,388,608
    constexpr size_t FLG_OFF = UBF_OFF + 8388608;          //     262,656
    constexpr size_t HR_OFF  = FLG_OFF + 262656;           //     524,288

    _Float16* XW  = (_Float16*)(ws + XW_OFF);
    float*    INP = (float*)(ws + INP_OFF);
    u16*      WBF = (u16*)(ws + WBF_OFF);
    u16*      UBF = (u16*)(ws + UBF_OFF);
    int*      flg = (int*)(ws + FLG_OFF);
    u64*      hring = (u64*)(ws + HR_OFF);

    init_flags<<<(4 * 513 * 32 + 255) / 256, 256, 0, stream>>>(flg);
    convert_x<<<2048, 256, 0, stream>>>(x, INP);
    convert_wu<<<dim3(64, 16, 8), 256, 0, stream>>>(W, U, WBF, UBF);
    gemm_xw<<<dim3(16, 256), 256, 0, stream>>>(INP, WBF, b, XW);
    fused<<<128, 256, 0, stream>>>(XW, WBF, UBF, b, INP, flg, hring, out + 16777216);
    transpose_out<<<2048, 256, 0, stream>>>(INP, out);
}